// Round 1
// baseline (1197.178 us; speedup 1.0000x reference)
//
#include <hip/hip_runtime.h>
#include <hip/hip_bf16.h>

typedef __bf16 bf16_t;
typedef __bf16 bf16x4 __attribute__((ext_vector_type(4)));
typedef __bf16 bf16x8 __attribute__((ext_vector_type(8)));
typedef float  f32x4  __attribute__((ext_vector_type(4)));

#define HEPS 1e-6f

// ---------------- small kernels ----------------

__global__ void cvt_f32_bf16_k(const float* __restrict__ src, bf16_t* __restrict__ dst, int n) {
    int i = blockIdx.x * 256 + threadIdx.x;
    if (i < n) dst[i] = (bf16_t)src[i];
}

// Dt0[bs][r][d] = Dinit[b][d][r]  (bs = b*2 + s)
__global__ void dinit_k(const float* __restrict__ Ds, const float* __restrict__ Dc,
                        bf16_t* __restrict__ Dt) {
    int bs = blockIdx.y;
    int b = bs >> 1;
    const float* src = ((bs & 1) ? Dc : Ds) + (size_t)b * 512 * 64;
    int idx = blockIdx.x * 256 + threadIdx.x;   // grid.x = 128 -> 32768 elems
    int r = idx & 63, d = idx >> 6;
    Dt[(size_t)bs * 64 * 512 + (size_t)r * 512 + d] = (bf16_t)src[d * 64 + r];
}

// xinv[bs][n] = 1 / (T * max(||X[:,n]||, EPS))
__global__ void xnorm_k(const bf16_t* __restrict__ X, float* __restrict__ xinv) {
    int bs = blockIdx.y;
    int n = blockIdx.x * 256 + threadIdx.x;     // grid.x = 16
    const bf16_t* Xb = X + (size_t)bs * 512 * 4096;
    float s = 0.f;
    for (int d = 0; d < 512; ++d) {
        float v = (float)Xb[(size_t)d * 4096 + n];
        s += v * v;
    }
    xinv[bs * 4096 + n] = 1.0f / (10.0f * fmaxf(sqrtf(s), HEPS));
}

// dinv[bs*64+r] = 1 / max(||Dt[r,:]||, EPS)   (one wave per row)
__global__ void dnorm_k(const bf16_t* __restrict__ Dt, float* __restrict__ dinv) {
    int gw = (blockIdx.x * 256 + threadIdx.x) >> 6;   // 1024 rows total, grid = 256
    int lane = threadIdx.x & 63;
    const bf16_t* row = Dt + (size_t)gw * 512;
    float s = 0.f;
    #pragma unroll
    for (int i = 0; i < 8; ++i) {
        float v = (float)row[lane + i * 64];
        s += v * v;
    }
    #pragma unroll
    for (int off = 32; off > 0; off >>= 1) s += __shfl_xor(s, off);
    if (lane == 0) dinv[gw] = 1.0f / fmaxf(sqrtf(s), HEPS);
}

// column softmax over r=64: C[r][n] and Ct[n][r] (both bf16)
__global__ void softmax_k(const float* __restrict__ S, const float* __restrict__ xinv,
                          const float* __restrict__ dinv,
                          bf16_t* __restrict__ C, bf16_t* __restrict__ Ct) {
    int bs = blockIdx.y;
    int n = blockIdx.x * 256 + threadIdx.x;
    const float* Sb = S + (size_t)bs * 64 * 4096;
    const float* di = dinv + bs * 64;
    float xi = xinv[bs * 4096 + n];
    float m = -1e30f, ssum = 0.f;
    for (int r = 0; r < 64; ++r) {
        float v = Sb[(size_t)r * 4096 + n] * di[r] * xi;
        float mn = fmaxf(m, v);
        ssum = ssum * __expf(m - mn) + __expf(v - mn);
        m = mn;
    }
    float rs = 1.0f / ssum;
    bf16_t* Cb  = C  + (size_t)bs * 64 * 4096;
    bf16_t* Ctb = Ct + (size_t)bs * 4096 * 64;
    for (int r = 0; r < 64; ++r) {
        float v = Sb[(size_t)r * 4096 + n] * di[r] * xi;
        float e = __expf(v - m) * rs;
        bf16_t eb = (bf16_t)e;
        Cb[(size_t)r * 4096 + n] = eb;
        Ctb[(size_t)n * 64 + r] = eb;
    }
}

// D2[bs][d][r] = Dt[bs][r][d] * dinv[bs*64+r]  (bf16)
__global__ void d2_k(const bf16_t* __restrict__ Dt, const float* __restrict__ dinv,
                     bf16_t* __restrict__ D2) {
    int bs = blockIdx.y;
    int idx = blockIdx.x * 256 + threadIdx.x;   // grid.x = 128 -> 32768
    int r = idx >> 9, d = idx & 511;
    float v = (float)Dt[(size_t)bs * 64 * 512 + (size_t)r * 512 + d] * dinv[bs * 64 + r];
    D2[(size_t)bs * 512 * 64 + (size_t)d * 64 + r] = (bf16_t)v;
}

// ---------------- MFMA GEMM ----------------
// C[m][j] = sum_k A[m][k] * B[k][j]
// BMODE 0: Bg is BT, row-major (N x K) bf16
// BMODE 1: Bg is B, row-major (K x N) bf16  (stage-transposed into LDS)
// BMODE 2: Bg is B, row-major (K x N) fp32  (stage-transposed + cvt)
// EPI 0: fp32 store          EPI 1: +bias, relu, bf16
// EPI 2: BN, relu, bf16      EPI 3: +bias, BN, coefA*h + coefB*shortcut, relu, fp32
// EPI 4: bf16 store          EPI 5: transposed bf16 store (Cout[j][m])
template<int BM, int BN, int WAVES_M, int WAVES_N, int BMODE, int EPI>
__launch_bounds__(256)
__global__ void gemm_k(const bf16_t* __restrict__ Ag, const void* __restrict__ Bg,
                       void* __restrict__ Cg, int M, int N, int K,
                       long aStride, long bStride, long cStride,
                       const float* __restrict__ ep0, const float* __restrict__ ep1,
                       const float* __restrict__ ep2, const float* __restrict__ ep3,
                       const float* __restrict__ ep4,
                       const float* __restrict__ coefA, const float* __restrict__ coefB,
                       const float* __restrict__ shortcutB, long shortcutStride)
{
    constexpr int BK = 32;
    constexpr int PAD = 40;                 // LDS row stride in shorts
    constexpr int WM = BM / WAVES_M;
    constexpr int WN = BN / WAVES_N;
    constexpr int FM = WM / 16;
    constexpr int FN = WN / 16;
    constexpr int AIT = (BM * BK / 8) / 256;
    constexpr int BIT = (BN * BK / 8) / 256;
    static_assert(AIT >= 1 && BIT >= 1, "tile too small");

    __shared__ bf16_t Alds[BM * PAD];
    __shared__ bf16_t Blds[BN * PAD];

    const int tid = threadIdx.x;
    const int wave = tid >> 6;
    const int lane = tid & 63;
    const int l15 = lane & 15;
    const int q = lane >> 4;

    const int bz = blockIdx.z;
    const int n0 = blockIdx.x * BN;
    const int m0 = blockIdx.y * BM;
    const int wm0 = (wave / WAVES_N) * WM;
    const int wn0 = (wave % WAVES_N) * WN;

    const bf16_t* A = Ag + (size_t)bz * (size_t)aStride;

    f32x4 acc[FM][FN];
    #pragma unroll
    for (int i = 0; i < FM; ++i)
        #pragma unroll
        for (int j = 0; j < FN; ++j)
            #pragma unroll
            for (int e = 0; e < 4; ++e) acc[i][j][e] = 0.f;

    const int nK = K / BK;
    for (int kk = 0; kk < nK; ++kk) {
        const int k0 = kk * BK;
        __syncthreads();
        // ---- stage A tile (BM x 32), vector 16B ----
        #pragma unroll
        for (int it = 0; it < AIT; ++it) {
            int cid = tid + it * 256;
            int row = cid >> 2;
            int ko = (cid & 3) * 8;
            bf16x8 v = *reinterpret_cast<const bf16x8*>(A + (size_t)(m0 + row) * K + k0 + ko);
            *reinterpret_cast<bf16x8*>(&Alds[row * PAD + ko]) = v;
        }
        // ---- stage B tile into Blds[n][k] ----
        if constexpr (BMODE == 0) {
            const bf16_t* BT = (const bf16_t*)Bg + (size_t)bz * (size_t)bStride;
            #pragma unroll
            for (int it = 0; it < BIT; ++it) {
                int cid = tid + it * 256;
                int row = cid >> 2;
                int ko = (cid & 3) * 8;
                bf16x8 v = *reinterpret_cast<const bf16x8*>(BT + (size_t)(n0 + row) * K + k0 + ko);
                *reinterpret_cast<bf16x8*>(&Blds[row * PAD + ko]) = v;
            }
        } else if constexpr (BMODE == 1) {
            const bf16_t* B = (const bf16_t*)Bg + (size_t)bz * (size_t)bStride;
            #pragma unroll
            for (int it = 0; it < BIT; ++it) {
                int cid = tid + it * 256;
                int krow = cid / (BN / 8);
                int nn = (cid % (BN / 8)) * 8;
                bf16x8 v = *reinterpret_cast<const bf16x8*>(B + (size_t)(k0 + krow) * N + n0 + nn);
                #pragma unroll
                for (int e = 0; e < 8; ++e) Blds[(nn + e) * PAD + krow] = v[e];
            }
        } else {
            const float* B = (const float*)Bg + (size_t)bz * (size_t)bStride;
            #pragma unroll
            for (int it = 0; it < BIT; ++it) {
                int cid = tid + it * 256;
                int krow = cid / (BN / 8);
                int nn = (cid % (BN / 8)) * 8;
                const float* p = B + (size_t)(k0 + krow) * N + n0 + nn;
                float4 v0 = *reinterpret_cast<const float4*>(p);
                float4 v1 = *reinterpret_cast<const float4*>(p + 4);
                Blds[(nn + 0) * PAD + krow] = (bf16_t)v0.x;
                Blds[(nn + 1) * PAD + krow] = (bf16_t)v0.y;
                Blds[(nn + 2) * PAD + krow] = (bf16_t)v0.z;
                Blds[(nn + 3) * PAD + krow] = (bf16_t)v0.w;
                Blds[(nn + 4) * PAD + krow] = (bf16_t)v1.x;
                Blds[(nn + 5) * PAD + krow] = (bf16_t)v1.y;
                Blds[(nn + 6) * PAD + krow] = (bf16_t)v1.z;
                Blds[(nn + 7) * PAD + krow] = (bf16_t)v1.w;
            }
        }
        __syncthreads();

        // ---- fragments + MFMA ----
        bf16x8 af[FM];
        bf16x8 bfr[FN];
        #pragma unroll
        for (int i = 0; i < FM; ++i) {
            const bf16_t* p = &Alds[(wm0 + 16 * i + l15) * PAD + 4 * q];
            bf16x4 lo = *reinterpret_cast<const bf16x4*>(p);
            bf16x4 hi = *reinterpret_cast<const bf16x4*>(p + 16);
            bf16x8 t;
            t[0] = lo[0]; t[1] = lo[1]; t[2] = lo[2]; t[3] = lo[3];
            t[4] = hi[0]; t[5] = hi[1]; t[6] = hi[2]; t[7] = hi[3];
            af[i] = t;
        }
        #pragma unroll
        for (int j = 0; j < FN; ++j) {
            const bf16_t* p = &Blds[(wn0 + 16 * j + l15) * PAD + 4 * q];
            bf16x4 lo = *reinterpret_cast<const bf16x4*>(p);
            bf16x4 hi = *reinterpret_cast<const bf16x4*>(p + 16);
            bf16x8 t;
            t[0] = lo[0]; t[1] = lo[1]; t[2] = lo[2]; t[3] = lo[3];
            t[4] = hi[0]; t[5] = hi[1]; t[6] = hi[2]; t[7] = hi[3];
            bfr[j] = t;
        }
        #pragma unroll
        for (int i = 0; i < FM; ++i)
            #pragma unroll
            for (int j = 0; j < FN; ++j)
                acc[i][j] = __builtin_amdgcn_mfma_f32_16x16x32_bf16(af[i], bfr[j], acc[i][j], 0, 0, 0);
    }

    // ---- epilogue ----
    if constexpr (EPI == 0) {
        float* C = (float*)Cg + (size_t)bz * (size_t)cStride;
        #pragma unroll
        for (int i = 0; i < FM; ++i) {
            int rowb = m0 + wm0 + 16 * i + 4 * q;
            #pragma unroll
            for (int j = 0; j < FN; ++j) {
                int col = n0 + wn0 + 16 * j + l15;
                #pragma unroll
                for (int e = 0; e < 4; ++e)
                    C[(size_t)(rowb + e) * N + col] = acc[i][j][e];
            }
        }
    } else if constexpr (EPI == 5) {
        bf16_t* C = (bf16_t*)Cg + (size_t)bz * (size_t)cStride;
        #pragma unroll
        for (int i = 0; i < FM; ++i) {
            int rowb = m0 + wm0 + 16 * i + 4 * q;
            #pragma unroll
            for (int j = 0; j < FN; ++j) {
                int col = n0 + wn0 + 16 * j + l15;
                bf16x4 v;
                #pragma unroll
                for (int e = 0; e < 4; ++e) v[e] = (bf16_t)acc[i][j][e];
                *reinterpret_cast<bf16x4*>(&C[(size_t)col * M + rowb]) = v;
            }
        }
    } else if constexpr (EPI == 3) {
        float* C = (float*)Cg + (size_t)bz * (size_t)cStride;
        float cA = coefA[0], cB = coefB[0];
        #pragma unroll
        for (int i = 0; i < FM; ++i) {
            int rowb = m0 + wm0 + 16 * i + 4 * q;
            #pragma unroll
            for (int j = 0; j < FN; ++j) {
                int col = n0 + wn0 + 16 * j + l15;
                #pragma unroll
                for (int e = 0; e < 4; ++e) {
                    int row = rowb + e;
                    float v = acc[i][j][e] + ep4[row];
                    float inv = ep0[row] * rsqrtf(ep3[row] + 1e-5f);
                    v = v * inv + (ep1[row] - ep2[row] * inv);
                    float sc = shortcutB[(size_t)bz * (size_t)shortcutStride + (size_t)row * N + col];
                    v = cA * v + cB * sc;
                    C[(size_t)row * N + col] = fmaxf(v, 0.f);
                }
            }
        }
    } else {
        bf16_t* C = (bf16_t*)Cg + (size_t)bz * (size_t)cStride;
        #pragma unroll
        for (int i = 0; i < FM; ++i) {
            int rowb = m0 + wm0 + 16 * i + 4 * q;
            #pragma unroll
            for (int j = 0; j < FN; ++j) {
                int col = n0 + wn0 + 16 * j + l15;
                #pragma unroll
                for (int e = 0; e < 4; ++e) {
                    int row = rowb + e;
                    float v = acc[i][j][e];
                    if constexpr (EPI == 1) {
                        v = fmaxf(v + ep0[row], 0.f);
                    } else if constexpr (EPI == 2) {
                        float inv = ep0[row] * rsqrtf(ep3[row] + 1e-5f);
                        v = v * inv + (ep1[row] - ep2[row] * inv);
                        v = fmaxf(v, 0.f);
                    }
                    C[(size_t)row * N + col] = (bf16_t)v;
                }
            }
        }
    }
}

// ---------------- host launcher ----------------

extern "C" void kernel_launch(void* const* d_in, const int* in_sizes, int n_in,
                              void* d_out, int out_size, void* d_ws, size_t ws_size,
                              hipStream_t stream) {
    const float* z        = (const float*)d_in[0];
    const float* lower_w  = (const float*)d_in[1];
    const float* lower_b  = (const float*)d_in[2];
    const float* Dinit_s  = (const float*)d_in[3];
    const float* Dinit_c  = (const float*)d_in[4];
    const float* cheese_w = (const float*)d_in[5];
    const float* ch_gamma = (const float*)d_in[6];
    const float* ch_beta  = (const float*)d_in[7];
    const float* ch_mean  = (const float*)d_in[8];
    const float* ch_var   = (const float*)d_in[9];
    const float* upper_w  = (const float*)d_in[10];
    const float* upper_b  = (const float*)d_in[11];
    const float* h_gamma  = (const float*)d_in[12];
    const float* h_beta   = (const float*)d_in[13];
    const float* h_mean   = (const float*)d_in[14];
    const float* h_var    = (const float*)d_in[15];
    const float* coef_ham = (const float*)d_in[16];
    const float* coef_sc  = (const float*)d_in[17];

    char* ws = (char*)d_ws;
    size_t off = 0;
    auto alloc = [&](size_t bytes) -> void* {
        void* p = ws + off;
        off += (bytes + 255) & ~(size_t)255;
        return p;
    };

    bf16_t* Wl   = (bf16_t*)alloc((size_t)1024 * 512 * 2);
    bf16_t* Wc   = (bf16_t*)alloc((size_t)1024 * 1024 * 2);
    bf16_t* Wu   = (bf16_t*)alloc((size_t)512 * 1024 * 2);
    bf16_t* Xbf  = (bf16_t*)alloc((size_t)8 * 1024 * 4096 * 2);   // also reused as Ych
    bf16_t* Yham = (bf16_t*)alloc((size_t)8 * 1024 * 4096 * 2);
    float*  Sbuf = (float*) alloc((size_t)16 * 64 * 4096 * 4);
    bf16_t* Cbf  = (bf16_t*)alloc((size_t)16 * 64 * 4096 * 2);
    bf16_t* Ctbf = (bf16_t*)alloc((size_t)16 * 4096 * 64 * 2);
    bf16_t* Dta  = (bf16_t*)alloc((size_t)16 * 64 * 512 * 2);
    bf16_t* Dtb  = (bf16_t*)alloc((size_t)16 * 64 * 512 * 2);
    bf16_t* D2   = (bf16_t*)alloc((size_t)16 * 512 * 64 * 2);
    float*  dinv = (float*) alloc((size_t)16 * 64 * 4);
    float*  xinv = (float*) alloc((size_t)16 * 4096 * 4);
    bf16_t* Ych  = Xbf;   // X dead after last XCt-GEMM

    dim3 blk(256);

    cvt_f32_bf16_k<<<2048, blk, 0, stream>>>(lower_w, Wl, 1024 * 512);
    cvt_f32_bf16_k<<<4096, blk, 0, stream>>>(cheese_w, Wc, 1024 * 1024);
    cvt_f32_bf16_k<<<2048, blk, 0, stream>>>(upper_w, Wu, 512 * 1024);
    dinit_k<<<dim3(128, 16), blk, 0, stream>>>(Dinit_s, Dinit_c, Dta);

    // G1: X = relu(Wl @ z + b), bf16   M=1024 N=4096 K=512, batch 8
    gemm_k<128, 128, 2, 2, 2, 1><<<dim3(32, 8, 8), blk, 0, stream>>>(
        Wl, (const void*)z, (void*)Xbf, 1024, 4096, 512,
        0L, (long)512 * 4096, (long)1024 * 4096,
        lower_b, nullptr, nullptr, nullptr, nullptr, nullptr, nullptr, nullptr, 0L);

    xnorm_k<<<dim3(16, 16), blk, 0, stream>>>(Xbf, xinv);

    bf16_t* cur = Dta;
    bf16_t* nxt = Dtb;
    for (int t = 0; t < 3; ++t) {
        dnorm_k<<<256, blk, 0, stream>>>(cur, dinv);
        // S = Dt @ X   M=64 N=4096 K=512, batch 16
        gemm_k<64, 256, 1, 4, 1, 0><<<dim3(16, 1, 16), blk, 0, stream>>>(
            cur, (const void*)Xbf, (void*)Sbuf, 64, 4096, 512,
            (long)64 * 512, (long)512 * 4096, (long)64 * 4096,
            nullptr, nullptr, nullptr, nullptr, nullptr, nullptr, nullptr, nullptr, 0L);
        softmax_k<<<dim3(16, 16), blk, 0, stream>>>(Sbuf, xinv, dinv, Cbf, Ctbf);
        // Dt_next[r][d] = (X @ C^T)[d][r]   M=512 N=64 K=4096, batch 16, transposed store
        gemm_k<64, 64, 2, 2, 0, 5><<<dim3(1, 8, 16), blk, 0, stream>>>(
            Xbf, (const void*)Cbf, (void*)nxt, 512, 64, 4096,
            (long)512 * 4096, (long)64 * 4096, (long)64 * 512,
            nullptr, nullptr, nullptr, nullptr, nullptr, nullptr, nullptr, nullptr, 0L);
        bf16_t* tmp = cur; cur = nxt; nxt = tmp;
    }
    dnorm_k<<<256, blk, 0, stream>>>(cur, dinv);
    d2_k<<<dim3(128, 16), blk, 0, stream>>>(cur, dinv, D2);

    // Xbar = D2 @ C -> Yham halves   M=512 N=4096 K=64, batch 16
    gemm_k<128, 128, 2, 2, 0, 4><<<dim3(32, 4, 16), blk, 0, stream>>>(
        D2, (const void*)Ctbf, (void*)Yham, 512, 4096, 64,
        (long)512 * 64, (long)4096 * 64, (long)512 * 4096,
        nullptr, nullptr, nullptr, nullptr, nullptr, nullptr, nullptr, nullptr, 0L);

    // G6: Ych = relu(bn(Wc @ Yham))   M=1024 N=4096 K=1024, batch 8
    gemm_k<128, 128, 2, 2, 1, 2><<<dim3(32, 8, 8), blk, 0, stream>>>(
        Wc, (const void*)Yham, (void*)Ych, 1024, 4096, 1024,
        0L, (long)1024 * 4096, (long)1024 * 4096,
        ch_gamma, ch_beta, ch_mean, ch_var, nullptr, nullptr, nullptr, nullptr, 0L);

    // G7: out = relu(coef_ham * bn(Wu @ Ych + ub) + coef_sc * z), fp32
    gemm_k<128, 128, 2, 2, 1, 3><<<dim3(32, 4, 8), blk, 0, stream>>>(
        Wu, (const void*)Ych, d_out, 512, 4096, 1024,
        0L, (long)1024 * 4096, (long)512 * 4096,
        h_gamma, h_beta, h_mean, h_var, upper_b, coef_ham, coef_sc, z, (long)512 * 4096);

    (void)in_sizes; (void)n_in; (void)out_size; (void)ws_size;
}

// Round 2
// 466.916 us; speedup vs baseline: 2.5640x; 2.5640x over previous
//
#include <hip/hip_runtime.h>
#include <hip/hip_bf16.h>

typedef __bf16 bf16_t;
typedef __bf16 bf16x4 __attribute__((ext_vector_type(4)));
typedef __bf16 bf16x8 __attribute__((ext_vector_type(8)));
typedef float  f32x4  __attribute__((ext_vector_type(4)));

#define HEPS 1e-6f

__device__ __forceinline__ void gload16(const bf16_t* g, bf16_t* l) {
    __builtin_amdgcn_global_load_lds(
        (const __attribute__((address_space(1))) unsigned int*)(g),
        (__attribute__((address_space(3))) unsigned int*)(l),
        16, 0, 0);
}

// ---------------- small kernels ----------------

__global__ void cvt_f32_bf16_k(const float* __restrict__ src, bf16_t* __restrict__ dst, int n) {
    int i = blockIdx.x * 256 + threadIdx.x;
    if (i < n) dst[i] = (bf16_t)src[i];
}

// fold BN params: chA/chB per cheese col; hA2/hB2 per upper row (bias+coef folded)
__global__ void prep_k(const float* __restrict__ chg, const float* __restrict__ chb,
                       const float* __restrict__ chm, const float* __restrict__ chv,
                       const float* __restrict__ hg, const float* __restrict__ hb,
                       const float* __restrict__ hm, const float* __restrict__ hv,
                       const float* __restrict__ ub, const float* __restrict__ cham,
                       float* __restrict__ chA, float* __restrict__ chB,
                       float* __restrict__ hA2, float* __restrict__ hB2) {
    int i = blockIdx.x * 256 + threadIdx.x;
    if (i < 1024) {
        float inv = chg[i] * rsqrtf(chv[i] + 1e-5f);
        chA[i] = inv;
        chB[i] = chb[i] - chm[i] * inv;
    }
    if (i < 512) {
        float inv = hg[i] * rsqrtf(hv[i] + 1e-5f);
        float cA = cham[0];
        hA2[i] = cA * inv;
        hB2[i] = cA * (fmaf(ub[i], inv, hb[i]) - hm[i] * inv);
    }
}

// z [b][512][4096] fp32 -> Zt [b][4096][512] bf16
__global__ void tz_k(const float* __restrict__ z, bf16_t* __restrict__ Zt) {
    __shared__ bf16_t t[64][68];
    int b = blockIdx.z, kt = blockIdx.y, nt = blockIdx.x;
    const float* src = z + ((size_t)b * 512 + kt * 64) * 4096 + nt * 64;
    int tid = threadIdx.x;
    int kr = tid >> 4;
    int nc = (tid & 15) * 4;
    #pragma unroll
    for (int it = 0; it < 4; ++it) {
        int k = kr + it * 16;
        float4 v = *(const float4*)&src[(size_t)k * 4096 + nc];
        t[nc + 0][k] = (bf16_t)v.x; t[nc + 1][k] = (bf16_t)v.y;
        t[nc + 2][k] = (bf16_t)v.z; t[nc + 3][k] = (bf16_t)v.w;
    }
    __syncthreads();
    bf16_t* dst = Zt + ((size_t)b * 4096 + nt * 64) * 512 + kt * 64;
    int nr = tid >> 4;
    int kc = (tid & 15) * 4;
    #pragma unroll
    for (int it = 0; it < 4; ++it) {
        int n = nr + it * 16;
        bf16x4 o;
        #pragma unroll
        for (int c = 0; c < 4; ++c) o[c] = t[n][kc + c];
        *(bf16x4*)&dst[(size_t)n * 512 + kc] = o;
    }
}

// Dt0[bs][r][d] = Dinit[b][d][r]
__global__ void dinit_k(const float* __restrict__ Ds, const float* __restrict__ Dc,
                        bf16_t* __restrict__ Dt) {
    int bs = blockIdx.y;
    int b = bs >> 1;
    const float* src = ((bs & 1) ? Dc : Ds) + (size_t)b * 512 * 64;
    int idx = blockIdx.x * 256 + threadIdx.x;
    int r = idx & 63, d = idx >> 6;
    Dt[(size_t)bs * 64 * 512 + (size_t)r * 512 + d] = (bf16_t)src[d * 64 + r];
}

// xinv[row] over Xt rows (16*4096 rows of 512)
__global__ void xnorm2_k(const bf16_t* __restrict__ Xt, float* __restrict__ xinv) {
    int gid = blockIdx.x * 4 + (threadIdx.x >> 6);
    int lane = threadIdx.x & 63;
    bf16x8 v = *(const bf16x8*)(Xt + (size_t)gid * 512 + lane * 8);
    float s = 0.f;
    #pragma unroll
    for (int e = 0; e < 8; ++e) { float f = (float)v[e]; s += f * f; }
    #pragma unroll
    for (int off = 32; off > 0; off >>= 1) s += __shfl_xor(s, off);
    if (lane == 0) xinv[gid] = 1.0f / (10.0f * fmaxf(sqrtf(s), HEPS));
}

// dinv over Dt rows (1024 rows of 512), wave per row
__global__ void dnorm_k(const bf16_t* __restrict__ Dt, float* __restrict__ dinv) {
    int gw = (blockIdx.x * 256 + threadIdx.x) >> 6;
    int lane = threadIdx.x & 63;
    bf16x8 v = *(const bf16x8*)(Dt + (size_t)gw * 512 + lane * 8);
    float s = 0.f;
    #pragma unroll
    for (int e = 0; e < 8; ++e) { float f = (float)v[e]; s += f * f; }
    #pragma unroll
    for (int off = 32; off > 0; off >>= 1) s += __shfl_xor(s, off);
    if (lane == 0) dinv[gw] = 1.0f / fmaxf(sqrtf(s), HEPS);
}

// sum 4 split-K partials -> Dt bf16, plus dinv of summed rows
__global__ void reduce_k(const float* __restrict__ P, bf16_t* __restrict__ Dt,
                         float* __restrict__ dinv) {
    int bsr = blockIdx.x;              // bs*64 + r
    int bs = bsr >> 6, r = bsr & 63;
    int lane = threadIdx.x;            // 64
    const float* base = P + ((size_t)(bs * 4) * 64 + r) * 512 + lane * 8;
    float s[8] = {0.f, 0.f, 0.f, 0.f, 0.f, 0.f, 0.f, 0.f};
    #pragma unroll
    for (int kc = 0; kc < 4; ++kc) {
        const float* p = base + (size_t)kc * 64 * 512;
        float4 u = *(const float4*)p;
        float4 w = *(const float4*)(p + 4);
        s[0] += u.x; s[1] += u.y; s[2] += u.z; s[3] += u.w;
        s[4] += w.x; s[5] += w.y; s[6] += w.z; s[7] += w.w;
    }
    bf16x8 o;
    float sq = 0.f;
    #pragma unroll
    for (int e = 0; e < 8; ++e) { sq += s[e] * s[e]; o[e] = (bf16_t)s[e]; }
    *(bf16x8*)&Dt[(size_t)bsr * 512 + lane * 8] = o;
    #pragma unroll
    for (int off = 32; off > 0; off >>= 1) sq += __shfl_xor(sq, off);
    if (lane == 0) dinv[bsr] = 1.0f / fmaxf(sqrtf(sq), HEPS);
}

// D2[bs][d][r] = Dt[bs][r][d] * dinv
__global__ void d2_k(const bf16_t* __restrict__ Dt, const float* __restrict__ dinv,
                     bf16_t* __restrict__ D2) {
    int bs = blockIdx.y;
    int idx = blockIdx.x * 256 + threadIdx.x;
    int r = idx >> 9, d = idx & 511;
    float v = (float)Dt[(size_t)bs * 64 * 512 + (size_t)r * 512 + d] * dinv[bs * 64 + r];
    D2[(size_t)bs * 512 * 64 + (size_t)d * 64 + r] = (bf16_t)v;
}

// ---------------- MFMA GEMM (m97-style: global_load_lds + linear LDS) ----------------
// C[m][n] = sum_k A[m][k]*B^T[n][k]; both operands row-major K-contiguous.
// EPI 1: G1 (bias+relu, dual store X + Xt)      EPI 2: cheese (col a*x+b, relu, bf16)
// EPI 3: upper (row a*x+b + cB*shortcut, relu, fp32)
// EPI 4: Xbar (bf16 store into Yt with (b,s) split)
// EPI 5: XCt split-K partial (transposed fp32)  EPI 6: S + fused column softmax -> C, Ct
template<int BM, int BN, int WAVES_M, int WAVES_N, int EPI>
__launch_bounds__(256)
__global__ void g2(const bf16_t* __restrict__ Ag, const bf16_t* __restrict__ Bg,
                   void* __restrict__ Cg, void* __restrict__ C2g,
                   const int M, const int N, const int K,
                   const int ldA, const int ldB, const int ldC,
                   const long aStride, const long bStride,
                   const long cStride, const long c2Stride,
                   const float* __restrict__ p0, const float* __restrict__ p1,
                   const float* __restrict__ scal,
                   const float* __restrict__ shortcut, const long sStride)
{
    constexpr int WM = BM / WAVES_M, WN = BN / WAVES_N;
    constexpr int FM = WM / 16, FN = WN / 16;
    constexpr int ASEG = BM / 64, BSEG = BN / 64;

    __shared__ __align__(64) bf16_t Al[BM * 32];
    __shared__ __align__(64) bf16_t Bl[BN * 32];
    __shared__ float dl[64];

    const int tid = threadIdx.x;
    const int wave = tid >> 6, lane = tid & 63;
    const int l15 = lane & 15, q = lane >> 4;
    const int lrow = lane >> 2, lcol = (lane & 3) * 8;

    const int bz = blockIdx.z;
    int bs = bz, ex = 0;
    if constexpr (EPI == 5) { bs = bz >> 2; ex = (bz & 3) * 1024; }

    const int n0 = blockIdx.x * BN;
    const int m0 = blockIdx.y * BM;
    const int wm0 = (wave / WAVES_N) * WM;
    const int wn0 = (wave % WAVES_N) * WN;

    const bf16_t* Ab = Ag + (size_t)bs * (size_t)aStride + ex;
    const bf16_t* Bb = Bg + (size_t)bs * (size_t)bStride + ex;

    if constexpr (EPI == 6) { if (tid < 64) dl[tid] = p0[bz * 64 + tid]; }

    f32x4 acc[FM][FN];
    #pragma unroll
    for (int i = 0; i < FM; ++i)
        #pragma unroll
        for (int j = 0; j < FN; ++j)
            #pragma unroll
            for (int e = 0; e < 4; ++e) acc[i][j][e] = 0.f;

    for (int k0 = 0; k0 < K; k0 += 32) {
        __syncthreads();
        #pragma unroll
        for (int t = 0; t < ASEG; ++t) {
            int seg = wave * ASEG + t;
            gload16(Ab + (size_t)(m0 + seg * 16 + lrow) * ldA + k0 + lcol, &Al[seg * 512]);
        }
        #pragma unroll
        for (int t = 0; t < BSEG; ++t) {
            int seg = wave * BSEG + t;
            gload16(Bb + (size_t)(n0 + seg * 16 + lrow) * ldB + k0 + lcol, &Bl[seg * 512]);
        }
        __syncthreads();

        bf16x8 af[FM], bfm[FN];
        #pragma unroll
        for (int i = 0; i < FM; ++i)
            af[i] = *(const bf16x8*)&Al[(wm0 + 16 * i + l15) * 32 + 8 * q];
        #pragma unroll
        for (int j = 0; j < FN; ++j)
            bfm[j] = *(const bf16x8*)&Bl[(wn0 + 16 * j + l15) * 32 + 8 * q];
        #pragma unroll
        for (int i = 0; i < FM; ++i)
            #pragma unroll
            for (int j = 0; j < FN; ++j)
                acc[i][j] = __builtin_amdgcn_mfma_f32_16x16x32_bf16(af[i], bfm[j], acc[i][j], 0, 0, 0);
    }

    int rowB[FM];
    #pragma unroll
    for (int i = 0; i < FM; ++i) rowB[i] = m0 + wm0 + 16 * i + 4 * q;
    const int colBase = n0 + wn0;

    if constexpr (EPI == 1) {
        bf16_t* X  = (bf16_t*)Cg  + (size_t)bz * (size_t)cStride;
        bf16_t* Xt = (bf16_t*)C2g + (size_t)bz * (size_t)c2Stride;
        #pragma unroll
        for (int i = 0; i < FM; ++i) {
            int rb = rowB[i];
            int s = rb >> 9, d0 = rb & 511;
            #pragma unroll
            for (int j = 0; j < FN; ++j) {
                int col = colBase + 16 * j + l15;
                bf16x4 t;
                #pragma unroll
                for (int e = 0; e < 4; ++e) {
                    float v = fmaxf(acc[i][j][e] + p0[rb + e], 0.f);
                    t[e] = (bf16_t)v;
                    X[(size_t)(rb + e) * ldC + col] = t[e];
                }
                *(bf16x4*)&Xt[((size_t)s * 4096 + col) * 512 + d0] = t;
            }
        }
    } else if constexpr (EPI == 2) {
        bf16_t* O = (bf16_t*)Cg + (size_t)bz * (size_t)cStride;
        #pragma unroll
        for (int j = 0; j < FN; ++j) {
            int col = colBase + 16 * j + l15;
            float a = p0[col], b = p1[col];
            #pragma unroll
            for (int i = 0; i < FM; ++i) {
                int rb = rowB[i];
                #pragma unroll
                for (int e = 0; e < 4; ++e) {
                    float v = fmaxf(fmaf(acc[i][j][e], a, b), 0.f);
                    O[(size_t)(rb + e) * ldC + col] = (bf16_t)v;
                }
            }
        }
    } else if constexpr (EPI == 3) {
        float* O = (float*)Cg + (size_t)bz * (size_t)cStride;
        const float* sc = shortcut + (size_t)bz * (size_t)sStride;
        float cB = scal[0];
        #pragma unroll
        for (int i = 0; i < FM; ++i) {
            int rb = rowB[i];
            #pragma unroll
            for (int e = 0; e < 4; ++e) {
                int row = rb + e;
                float a = p0[row], b = p1[row];
                #pragma unroll
                for (int j = 0; j < FN; ++j) {
                    int col = colBase + 16 * j + l15;
                    float v = fmaf(acc[i][j][e], a, b) + cB * sc[(size_t)row * ldC + col];
                    O[(size_t)row * ldC + col] = fmaxf(v, 0.f);
                }
            }
        }
    } else if constexpr (EPI == 4) {
        bf16_t* O = (bf16_t*)Cg + (size_t)(bz >> 1) * (size_t)cStride + (bz & 1) * 512;
        #pragma unroll
        for (int i = 0; i < FM; ++i) {
            int rb = rowB[i];
            #pragma unroll
            for (int j = 0; j < FN; ++j) {
                int col = colBase + 16 * j + l15;
                #pragma unroll
                for (int e = 0; e < 4; ++e)
                    O[(size_t)(rb + e) * ldC + col] = (bf16_t)acc[i][j][e];
            }
        }
    } else if constexpr (EPI == 5) {
        float* O = (float*)Cg + (size_t)bz * (size_t)cStride;
        #pragma unroll
        for (int i = 0; i < FM; ++i) {
            int rb = rowB[i];
            #pragma unroll
            for (int j = 0; j < FN; ++j) {
                int col = colBase + 16 * j + l15;
                *(f32x4*)&O[(size_t)col * ldC + rb] = acc[i][j];
            }
        }
    } else if constexpr (EPI == 6) {
        bf16_t* Cc = (bf16_t*)Cg  + (size_t)bz * (size_t)cStride;
        bf16_t* Ct = (bf16_t*)C2g + (size_t)bz * (size_t)c2Stride;
        #pragma unroll
        for (int j = 0; j < FN; ++j) {
            int col = colBase + 16 * j + l15;
            float xi = p1[bz * 4096 + col];
            float mx = -1e30f;
            #pragma unroll
            for (int i = 0; i < FM; ++i)
                #pragma unroll
                for (int e = 0; e < 4; ++e) {
                    float v = acc[i][j][e] * dl[rowB[i] + e] * xi;
                    acc[i][j][e] = v;
                    mx = fmaxf(mx, v);
                }
            mx = fmaxf(mx, __shfl_xor(mx, 16));
            mx = fmaxf(mx, __shfl_xor(mx, 32));
            float sm = 0.f;
            #pragma unroll
            for (int i = 0; i < FM; ++i)
                #pragma unroll
                for (int e = 0; e < 4; ++e) {
                    float p = __expf(acc[i][j][e] - mx);
                    acc[i][j][e] = p;
                    sm += p;
                }
            sm += __shfl_xor(sm, 16);
            sm += __shfl_xor(sm, 32);
            float rs = 1.0f / sm;
            #pragma unroll
            for (int i = 0; i < FM; ++i) {
                int rb = rowB[i];
                bf16x4 t;
                #pragma unroll
                for (int e = 0; e < 4; ++e) {
                    t[e] = (bf16_t)(acc[i][j][e] * rs);
                    Cc[(size_t)(rb + e) * ldC + col] = t[e];
                }
                *(bf16x4*)&Ct[(size_t)col * 64 + rb] = t;
            }
        }
    }
}

// ---------------- host launcher ----------------

extern "C" void kernel_launch(void* const* d_in, const int* in_sizes, int n_in,
                              void* d_out, int out_size, void* d_ws, size_t ws_size,
                              hipStream_t stream) {
    const float* z        = (const float*)d_in[0];
    const float* lower_w  = (const float*)d_in[1];
    const float* lower_b  = (const float*)d_in[2];
    const float* Dinit_s  = (const float*)d_in[3];
    const float* Dinit_c  = (const float*)d_in[4];
    const float* cheese_w = (const float*)d_in[5];
    const float* ch_gamma = (const float*)d_in[6];
    const float* ch_beta  = (const float*)d_in[7];
    const float* ch_mean  = (const float*)d_in[8];
    const float* ch_var   = (const float*)d_in[9];
    const float* upper_w  = (const float*)d_in[10];
    const float* upper_b  = (const float*)d_in[11];
    const float* h_gamma  = (const float*)d_in[12];
    const float* h_beta   = (const float*)d_in[13];
    const float* h_mean   = (const float*)d_in[14];
    const float* h_var    = (const float*)d_in[15];
    const float* coef_ham = (const float*)d_in[16];
    const float* coef_sc  = (const float*)d_in[17];

    char* ws = (char*)d_ws;
    size_t off = 0;
    auto alloc = [&](size_t bytes) -> void* {
        void* p = ws + off;
        off += (bytes + 255) & ~(size_t)255;
        return p;
    };

    bf16_t* Wl   = (bf16_t*)alloc((size_t)1024 * 512 * 2);
    bf16_t* Wc   = (bf16_t*)alloc((size_t)1024 * 1024 * 2);
    bf16_t* Wu   = (bf16_t*)alloc((size_t)512 * 1024 * 2);
    float*  chA  = (float*) alloc(1024 * 4);
    float*  chB  = (float*) alloc(1024 * 4);
    float*  hA2  = (float*) alloc(512 * 4);
    float*  hB2  = (float*) alloc(512 * 4);
    float*  dinv = (float*) alloc(1024 * 4);
    float*  xinv = (float*) alloc((size_t)16 * 4096 * 4);
    bf16_t* Xbf  = (bf16_t*)alloc((size_t)8 * 1024 * 4096 * 2);   // later: Ycht
    bf16_t* Xt   = (bf16_t*)alloc((size_t)16 * 4096 * 512 * 2);
    bf16_t* YtZ  = (bf16_t*)alloc((size_t)8 * 4096 * 1024 * 2);   // Zt early, Yt late
    bf16_t* Cb   = (bf16_t*)alloc((size_t)16 * 64 * 4096 * 2);
    bf16_t* Ctb  = (bf16_t*)alloc((size_t)16 * 4096 * 64 * 2);
    float*  P    = (float*) alloc((size_t)64 * 64 * 512 * 4);
    bf16_t* Dta  = (bf16_t*)alloc((size_t)16 * 64 * 512 * 2);
    bf16_t* Dtb  = (bf16_t*)alloc((size_t)16 * 64 * 512 * 2);
    bf16_t* D2   = (bf16_t*)alloc((size_t)16 * 512 * 64 * 2);
    bf16_t* Zt   = YtZ;
    bf16_t* Yt   = YtZ;
    bf16_t* Ycht = Xbf;

    dim3 blk(256);

    cvt_f32_bf16_k<<<2048, blk, 0, stream>>>(lower_w, Wl, 1024 * 512);
    cvt_f32_bf16_k<<<4096, blk, 0, stream>>>(cheese_w, Wc, 1024 * 1024);
    cvt_f32_bf16_k<<<2048, blk, 0, stream>>>(upper_w, Wu, 512 * 1024);
    prep_k<<<4, blk, 0, stream>>>(ch_gamma, ch_beta, ch_mean, ch_var,
                                  h_gamma, h_beta, h_mean, h_var,
                                  upper_b, coef_ham, chA, chB, hA2, hB2);
    tz_k<<<dim3(64, 8, 8), blk, 0, stream>>>(z, Zt);
    dinit_k<<<dim3(128, 16), blk, 0, stream>>>(Dinit_s, Dinit_c, Dta);

    // G1: X = relu(Wl @ z + b)  -> X [b][1024][4096] and Xt [bs][4096][512]
    g2<128, 128, 2, 2, 1><<<dim3(32, 8, 8), blk, 0, stream>>>(
        Wl, Zt, (void*)Xbf, (void*)Xt, 1024, 4096, 512,
        512, 512, 4096,
        0L, (long)4096 * 512, (long)1024 * 4096, (long)2 * 4096 * 512,
        lower_b, nullptr, nullptr, nullptr, 0L);

    xnorm2_k<<<16384, blk, 0, stream>>>(Xt, xinv);
    dnorm_k<<<256, blk, 0, stream>>>(Dta, dinv);

    bf16_t* cur = Dta;
    bf16_t* nxt = Dtb;
    for (int t = 0; t < 3; ++t) {
        // S + fused softmax -> C [bs][64][4096], Ct [bs][4096][64]
        g2<64, 256, 1, 4, 6><<<dim3(16, 1, 16), blk, 0, stream>>>(
            cur, Xt, (void*)Cb, (void*)Ctb, 64, 4096, 512,
            512, 512, 4096,
            (long)64 * 512, (long)4096 * 512, (long)64 * 4096, (long)4096 * 64,
            dinv, xinv, nullptr, nullptr, 0L);
        // XCt split-K=4 partials: P[bz][r][d] (transposed fp32)
        g2<128, 64, 2, 2, 5><<<dim3(1, 4, 64), blk, 0, stream>>>(
            Xbf, Cb, (void*)P, nullptr, 512, 64, 1024,
            4096, 4096, 512,
            (long)512 * 4096, (long)64 * 4096, (long)64 * 512, 0L,
            nullptr, nullptr, nullptr, nullptr, 0L);
        reduce_k<<<1024, dim3(64), 0, stream>>>(P, nxt, dinv);
        bf16_t* tmp = cur; cur = nxt; nxt = tmp;
    }

    d2_k<<<dim3(128, 16), blk, 0, stream>>>(cur, dinv, D2);

    // Xbar^T = Ct @ D2^T -> Yt [b][4096][1024] (cols s*512+d)
    g2<128, 128, 2, 2, 4><<<dim3(4, 32, 16), blk, 0, stream>>>(
        Ctb, D2, (void*)Yt, nullptr, 4096, 512, 64,
        64, 64, 1024,
        (long)4096 * 64, (long)512 * 64, (long)4096 * 1024, 0L,
        nullptr, nullptr, nullptr, nullptr, 0L);

    // cheese: Ycht[n][c] = relu(bn(Yt[n][:] @ Wc^T))
    g2<128, 128, 2, 2, 2><<<dim3(8, 32, 8), blk, 0, stream>>>(
        Yt, Wc, (void*)Ycht, nullptr, 4096, 1024, 1024,
        1024, 1024, 1024,
        (long)4096 * 1024, 0L, (long)4096 * 1024, 0L,
        chA, chB, nullptr, nullptr, 0L);

    // upper: out = relu(hA2*(Wu @ Ych) + hB2 + cB*z)  fp32
    g2<128, 128, 2, 2, 3><<<dim3(32, 4, 8), blk, 0, stream>>>(
        Wu, Ycht, d_out, nullptr, 512, 4096, 1024,
        1024, 1024, 4096,
        0L, (long)4096 * 1024, (long)512 * 4096, 0L,
        hA2, hB2, coef_sc, z, (long)512 * 4096);

    (void)in_sizes; (void)n_in; (void)out_size; (void)ws_size;
}

// Round 3
// 454.585 us; speedup vs baseline: 2.6336x; 1.0271x over previous
//
#include <hip/hip_runtime.h>
#include <hip/hip_bf16.h>

typedef __bf16 bf16_t;
typedef __bf16 bf16x4 __attribute__((ext_vector_type(4)));
typedef __bf16 bf16x8 __attribute__((ext_vector_type(8)));
typedef float  f32x4  __attribute__((ext_vector_type(4)));

#define HEPS 1e-6f

__device__ __forceinline__ void gload16(const bf16_t* g, bf16_t* l) {
    __builtin_amdgcn_global_load_lds(
        (const __attribute__((address_space(1))) unsigned int*)(g),
        (__attribute__((address_space(3))) unsigned int*)(l),
        16, 0, 0);
}

// ---------------- small kernels ----------------

__global__ void cvt_f32_bf16_k(const float* __restrict__ src, bf16_t* __restrict__ dst, int n) {
    int i = blockIdx.x * 256 + threadIdx.x;
    if (i < n) dst[i] = (bf16_t)src[i];
}

__global__ void prep_k(const float* __restrict__ chg, const float* __restrict__ chb,
                       const float* __restrict__ chm, const float* __restrict__ chv,
                       const float* __restrict__ hg, const float* __restrict__ hb,
                       const float* __restrict__ hm, const float* __restrict__ hv,
                       const float* __restrict__ ub, const float* __restrict__ cham,
                       float* __restrict__ chA, float* __restrict__ chB,
                       float* __restrict__ hA2, float* __restrict__ hB2) {
    int i = blockIdx.x * 256 + threadIdx.x;
    if (i < 1024) {
        float inv = chg[i] * rsqrtf(chv[i] + 1e-5f);
        chA[i] = inv;
        chB[i] = chb[i] - chm[i] * inv;
    }
    if (i < 512) {
        float inv = hg[i] * rsqrtf(hv[i] + 1e-5f);
        float cA = cham[0];
        hA2[i] = cA * inv;
        hB2[i] = cA * (fmaf(ub[i], inv, hb[i]) - hm[i] * inv);
    }
}

// z [b][512][4096] fp32 -> Zt [b][4096][512] bf16
__global__ void tz_k(const float* __restrict__ z, bf16_t* __restrict__ Zt) {
    __shared__ bf16_t t[64][68];
    int b = blockIdx.z, kt = blockIdx.y, nt = blockIdx.x;
    const float* src = z + ((size_t)b * 512 + kt * 64) * 4096 + nt * 64;
    int tid = threadIdx.x;
    int kr = tid >> 4;
    int nc = (tid & 15) * 4;
    #pragma unroll
    for (int it = 0; it < 4; ++it) {
        int k = kr + it * 16;
        float4 v = *(const float4*)&src[(size_t)k * 4096 + nc];
        t[nc + 0][k] = (bf16_t)v.x; t[nc + 1][k] = (bf16_t)v.y;
        t[nc + 2][k] = (bf16_t)v.z; t[nc + 3][k] = (bf16_t)v.w;
    }
    __syncthreads();
    bf16_t* dst = Zt + ((size_t)b * 4096 + nt * 64) * 512 + kt * 64;
    int nr = tid >> 4;
    int kc = (tid & 15) * 4;
    #pragma unroll
    for (int it = 0; it < 4; ++it) {
        int n = nr + it * 16;
        bf16x4 o;
        #pragma unroll
        for (int c = 0; c < 4; ++c) o[c] = t[n][kc + c];
        *(bf16x4*)&dst[(size_t)n * 512 + kc] = o;
    }
}

__global__ void dinit_k(const float* __restrict__ Ds, const float* __restrict__ Dc,
                        bf16_t* __restrict__ Dt) {
    int bs = blockIdx.y;
    int b = bs >> 1;
    const float* src = ((bs & 1) ? Dc : Ds) + (size_t)b * 512 * 64;
    int idx = blockIdx.x * 256 + threadIdx.x;
    int r = idx & 63, d = idx >> 6;
    Dt[(size_t)bs * 64 * 512 + (size_t)r * 512 + d] = (bf16_t)src[d * 64 + r];
}

__global__ void xnorm2_k(const bf16_t* __restrict__ Xt, float* __restrict__ xinv) {
    int gid = blockIdx.x * 4 + (threadIdx.x >> 6);
    int lane = threadIdx.x & 63;
    bf16x8 v = *(const bf16x8*)(Xt + (size_t)gid * 512 + lane * 8);
    float s = 0.f;
    #pragma unroll
    for (int e = 0; e < 8; ++e) { float f = (float)v[e]; s += f * f; }
    #pragma unroll
    for (int off = 32; off > 0; off >>= 1) s += __shfl_xor(s, off);
    if (lane == 0) xinv[gid] = 1.0f / (10.0f * fmaxf(sqrtf(s), HEPS));
}

__global__ void dnorm_k(const bf16_t* __restrict__ Dt, float* __restrict__ dinv) {
    int gw = (blockIdx.x * 256 + threadIdx.x) >> 6;
    int lane = threadIdx.x & 63;
    bf16x8 v = *(const bf16x8*)(Dt + (size_t)gw * 512 + lane * 8);
    float s = 0.f;
    #pragma unroll
    for (int e = 0; e < 8; ++e) { float f = (float)v[e]; s += f * f; }
    #pragma unroll
    for (int off = 32; off > 0; off >>= 1) s += __shfl_xor(s, off);
    if (lane == 0) dinv[gw] = 1.0f / fmaxf(sqrtf(s), HEPS);
}

// sum 4 split-K partials -> Dt bf16, plus dinv of summed rows
__global__ void reduce_k(const float* __restrict__ P, bf16_t* __restrict__ Dt,
                         float* __restrict__ dinv) {
    int bsr = blockIdx.x;
    int bs = bsr >> 6, r = bsr & 63;
    int lane = threadIdx.x;
    const float* base = P + ((size_t)(bs * 4) * 64 + r) * 512 + lane * 8;
    float s[8] = {0.f, 0.f, 0.f, 0.f, 0.f, 0.f, 0.f, 0.f};
    #pragma unroll
    for (int kc = 0; kc < 4; ++kc) {
        const float* p = base + (size_t)kc * 64 * 512;
        float4 u = *(const float4*)p;
        float4 w = *(const float4*)(p + 4);
        s[0] += u.x; s[1] += u.y; s[2] += u.z; s[3] += u.w;
        s[4] += w.x; s[5] += w.y; s[6] += w.z; s[7] += w.w;
    }
    bf16x8 o;
    float sq = 0.f;
    #pragma unroll
    for (int e = 0; e < 8; ++e) { sq += s[e] * s[e]; o[e] = (bf16_t)s[e]; }
    *(bf16x8*)&Dt[(size_t)bsr * 512 + lane * 8] = o;
    #pragma unroll
    for (int off = 32; off > 0; off >>= 1) sq += __shfl_xor(sq, off);
    if (lane == 0) dinv[bsr] = 1.0f / fmaxf(sqrtf(sq), HEPS);
}

__global__ void d2_k(const bf16_t* __restrict__ Dt, const float* __restrict__ dinv,
                     bf16_t* __restrict__ D2) {
    int bs = blockIdx.y;
    int idx = blockIdx.x * 256 + threadIdx.x;
    int r = idx >> 9, d = idx & 511;
    float v = (float)Dt[(size_t)bs * 64 * 512 + (size_t)r * 512 + d] * dinv[bs * 64 + r];
    D2[(size_t)bs * 512 * 64 + (size_t)d * 64 + r] = (bf16_t)v;
}

// ---------------- MFMA GEMM (m97-style + XCD-chunked swizzle) ----------------
// C[m][n] = sum_k A[m][k]*B^T[n][k]; both operands row-major K-contiguous.
// ORDER 0: x-fast within batch (A-panel reused across consecutive blocks)
// ORDER 1: y-fast within batch (B-panel reused across consecutive blocks)
// EPI 1: G1 (bias+relu, dual store X + Xt)      EPI 2: cheese (col a*x+b, relu, bf16)
// EPI 3: upper (row a*x+b + cB*shortcut, relu, fp32)
// EPI 4: Xbar (bf16 store with (b,s) split)
// EPI 5: XCt split-K partial (transposed fp32)  EPI 6: S + fused column softmax -> C[, Ct]
template<int BM, int BN, int WAVES_M, int WAVES_N, int EPI, int ORDER>
__launch_bounds__(256)
__global__ void g2(const bf16_t* __restrict__ Ag, const bf16_t* __restrict__ Bg,
                   void* __restrict__ Cg, void* __restrict__ C2g,
                   const int M, const int N, const int K,
                   const int ldA, const int ldB, const int ldC,
                   const long aStride, const long bStride,
                   const long cStride, const long c2Stride,
                   const float* __restrict__ p0, const float* __restrict__ p1,
                   const float* __restrict__ scal,
                   const float* __restrict__ shortcut, const long sStride)
{
    constexpr int WM = BM / WAVES_M, WN = BN / WAVES_N;
    constexpr int FM = WM / 16, FN = WN / 16;
    constexpr int ASEG = BM / 64, BSEG = BN / 64;

    __shared__ __align__(64) bf16_t Al[BM * 32];
    __shared__ __align__(64) bf16_t Bl[BN * 32];
    __shared__ float dl[64];

    const int tid = threadIdx.x;
    const int wave = tid >> 6, lane = tid & 63;
    const int l15 = lane & 15, q = lane >> 4;
    const int lrow = lane >> 2, lcol = (lane & 3) * 8;

    // ---- XCD-chunked bijective remap (m204) ----
    const int gx = gridDim.x, gy = gridDim.y;
    const int per = gx * gy;
    const int nwg = per * gridDim.z;
    const int g = blockIdx.z * per + blockIdx.y * gx + blockIdx.x;
    const int qq = nwg >> 3, rr = nwg & 7;
    const int xcd = g & 7, jj = g >> 3;
    const int w = (xcd < rr ? xcd * (qq + 1) : rr * (qq + 1) + (xcd - rr) * qq) + jj;
    const int bz = w / per;
    const int rem = w - bz * per;
    int bx, by;
    if constexpr (ORDER == 0) { by = rem / gx; bx = rem - by * gx; }
    else                      { bx = rem / gy; by = rem - bx * gy; }

    int bs = bz, ex = 0;
    if constexpr (EPI == 5) { bs = bz >> 2; ex = (bz & 3) * 1024; }

    const int n0 = bx * BN;
    const int m0 = by * BM;
    const int wm0 = (wave / WAVES_N) * WM;
    const int wn0 = (wave % WAVES_N) * WN;

    const bf16_t* Ab = Ag + (size_t)bs * (size_t)aStride + ex;
    const bf16_t* Bb = Bg + (size_t)bs * (size_t)bStride + ex;

    if constexpr (EPI == 6) { if (tid < 64) dl[tid] = p0[bz * 64 + tid]; }

    f32x4 acc[FM][FN];
    #pragma unroll
    for (int i = 0; i < FM; ++i)
        #pragma unroll
        for (int j = 0; j < FN; ++j)
            #pragma unroll
            for (int e = 0; e < 4; ++e) acc[i][j][e] = 0.f;

    for (int k0 = 0; k0 < K; k0 += 32) {
        __syncthreads();
        #pragma unroll
        for (int t = 0; t < ASEG; ++t) {
            int seg = wave * ASEG + t;
            gload16(Ab + (size_t)(m0 + seg * 16 + lrow) * ldA + k0 + lcol, &Al[seg * 512]);
        }
        #pragma unroll
        for (int t = 0; t < BSEG; ++t) {
            int seg = wave * BSEG + t;
            gload16(Bb + (size_t)(n0 + seg * 16 + lrow) * ldB + k0 + lcol, &Bl[seg * 512]);
        }
        __syncthreads();

        bf16x8 af[FM], bfm[FN];
        #pragma unroll
        for (int i = 0; i < FM; ++i)
            af[i] = *(const bf16x8*)&Al[(wm0 + 16 * i + l15) * 32 + 8 * q];
        #pragma unroll
        for (int j = 0; j < FN; ++j)
            bfm[j] = *(const bf16x8*)&Bl[(wn0 + 16 * j + l15) * 32 + 8 * q];
        #pragma unroll
        for (int i = 0; i < FM; ++i)
            #pragma unroll
            for (int j = 0; j < FN; ++j)
                acc[i][j] = __builtin_amdgcn_mfma_f32_16x16x32_bf16(af[i], bfm[j], acc[i][j], 0, 0, 0);
    }

    int rowB[FM];
    #pragma unroll
    for (int i = 0; i < FM; ++i) rowB[i] = m0 + wm0 + 16 * i + 4 * q;
    const int colBase = n0 + wn0;

    if constexpr (EPI == 1) {
        bf16_t* X  = (bf16_t*)Cg  + (size_t)bz * (size_t)cStride;
        bf16_t* Xt = (bf16_t*)C2g + (size_t)bz * (size_t)c2Stride;
        #pragma unroll
        for (int i = 0; i < FM; ++i) {
            int rb = rowB[i];
            int s = rb >> 9, d0 = rb & 511;
            #pragma unroll
            for (int j = 0; j < FN; ++j) {
                int col = colBase + 16 * j + l15;
                bf16x4 t;
                #pragma unroll
                for (int e = 0; e < 4; ++e) {
                    float v = fmaxf(acc[i][j][e] + p0[rb + e], 0.f);
                    t[e] = (bf16_t)v;
                    X[(size_t)(rb + e) * ldC + col] = t[e];
                }
                *(bf16x4*)&Xt[((size_t)s * 4096 + col) * 512 + d0] = t;
            }
        }
    } else if constexpr (EPI == 2) {
        bf16_t* O = (bf16_t*)Cg + (size_t)bz * (size_t)cStride;
        #pragma unroll
        for (int j = 0; j < FN; ++j) {
            int col = colBase + 16 * j + l15;
            float a = p0[col], b = p1[col];
            #pragma unroll
            for (int i = 0; i < FM; ++i) {
                int rb = rowB[i];
                #pragma unroll
                for (int e = 0; e < 4; ++e) {
                    float v = fmaxf(fmaf(acc[i][j][e], a, b), 0.f);
                    O[(size_t)(rb + e) * ldC + col] = (bf16_t)v;
                }
            }
        }
    } else if constexpr (EPI == 3) {
        float* O = (float*)Cg + (size_t)bz * (size_t)cStride;
        const float* sc = shortcut + (size_t)bz * (size_t)sStride;
        float cB = scal[0];
        #pragma unroll
        for (int i = 0; i < FM; ++i) {
            int rb = rowB[i];
            #pragma unroll
            for (int e = 0; e < 4; ++e) {
                int row = rb + e;
                float a = p0[row], b = p1[row];
                #pragma unroll
                for (int j = 0; j < FN; ++j) {
                    int col = colBase + 16 * j + l15;
                    float v = fmaf(acc[i][j][e], a, b) + cB * sc[(size_t)row * ldC + col];
                    O[(size_t)row * ldC + col] = fmaxf(v, 0.f);
                }
            }
        }
    } else if constexpr (EPI == 4) {
        bf16_t* O = (bf16_t*)Cg + (size_t)(bz >> 1) * (size_t)cStride + (bz & 1) * 512;
        #pragma unroll
        for (int i = 0; i < FM; ++i) {
            int rb = rowB[i];
            #pragma unroll
            for (int j = 0; j < FN; ++j) {
                int col = colBase + 16 * j + l15;
                #pragma unroll
                for (int e = 0; e < 4; ++e)
                    O[(size_t)(rb + e) * ldC + col] = (bf16_t)acc[i][j][e];
            }
        }
    } else if constexpr (EPI == 5) {
        float* O = (float*)Cg + (size_t)bz * (size_t)cStride;
        #pragma unroll
        for (int i = 0; i < FM; ++i) {
            int rb = rowB[i];
            #pragma unroll
            for (int j = 0; j < FN; ++j) {
                int col = colBase + 16 * j + l15;
                *(f32x4*)&O[(size_t)col * ldC + rb] = acc[i][j];
            }
        }
    } else if constexpr (EPI == 6) {
        bf16_t* Cc = (bf16_t*)Cg  + (size_t)bz * (size_t)cStride;
        bf16_t* Ct = (bf16_t*)C2g + (size_t)bz * (size_t)c2Stride;
        const bool doCt = (C2g != nullptr);
        #pragma unroll
        for (int j = 0; j < FN; ++j) {
            int col = colBase + 16 * j + l15;
            float xi = p1[bz * 4096 + col];
            float mx = -1e30f;
            #pragma unroll
            for (int i = 0; i < FM; ++i)
                #pragma unroll
                for (int e = 0; e < 4; ++e) {
                    float v = acc[i][j][e] * dl[rowB[i] + e] * xi;
                    acc[i][j][e] = v;
                    mx = fmaxf(mx, v);
                }
            mx = fmaxf(mx, __shfl_xor(mx, 16));
            mx = fmaxf(mx, __shfl_xor(mx, 32));
            float sm = 0.f;
            #pragma unroll
            for (int i = 0; i < FM; ++i)
                #pragma unroll
                for (int e = 0; e < 4; ++e) {
                    float p = __expf(acc[i][j][e] - mx);
                    acc[i][j][e] = p;
                    sm += p;
                }
            sm += __shfl_xor(sm, 16);
            sm += __shfl_xor(sm, 32);
            float rs = 1.0f / sm;
            #pragma unroll
            for (int i = 0; i < FM; ++i) {
                int rb = rowB[i];
                bf16x4 t;
                #pragma unroll
                for (int e = 0; e < 4; ++e) {
                    t[e] = (bf16_t)(acc[i][j][e] * rs);
                    Cc[(size_t)(rb + e) * ldC + col] = t[e];
                }
                if (doCt) *(bf16x4*)&Ct[(size_t)col * 64 + rb] = t;
            }
        }
    }
}

// ---------------- host launcher ----------------

extern "C" void kernel_launch(void* const* d_in, const int* in_sizes, int n_in,
                              void* d_out, int out_size, void* d_ws, size_t ws_size,
                              hipStream_t stream) {
    const float* z        = (const float*)d_in[0];
    const float* lower_w  = (const float*)d_in[1];
    const float* lower_b  = (const float*)d_in[2];
    const float* Dinit_s  = (const float*)d_in[3];
    const float* Dinit_c  = (const float*)d_in[4];
    const float* cheese_w = (const float*)d_in[5];
    const float* ch_gamma = (const float*)d_in[6];
    const float* ch_beta  = (const float*)d_in[7];
    const float* ch_mean  = (const float*)d_in[8];
    const float* ch_var   = (const float*)d_in[9];
    const float* upper_w  = (const float*)d_in[10];
    const float* upper_b  = (const float*)d_in[11];
    const float* h_gamma  = (const float*)d_in[12];
    const float* h_beta   = (const float*)d_in[13];
    const float* h_mean   = (const float*)d_in[14];
    const float* h_var    = (const float*)d_in[15];
    const float* coef_ham = (const float*)d_in[16];
    const float* coef_sc  = (const float*)d_in[17];

    char* ws = (char*)d_ws;
    size_t off = 0;
    auto alloc = [&](size_t bytes) -> void* {
        void* p = ws + off;
        off += (bytes + 255) & ~(size_t)255;
        return p;
    };

    bf16_t* Wl   = (bf16_t*)alloc((size_t)1024 * 512 * 2);
    bf16_t* Wc   = (bf16_t*)alloc((size_t)1024 * 1024 * 2);
    bf16_t* Wu   = (bf16_t*)alloc((size_t)512 * 1024 * 2);
    float*  chA  = (float*) alloc(1024 * 4);
    float*  chB  = (float*) alloc(1024 * 4);
    float*  hA2  = (float*) alloc(512 * 4);
    float*  hB2  = (float*) alloc(512 * 4);
    float*  dinv = (float*) alloc(1024 * 4);
    float*  xinv = (float*) alloc((size_t)16 * 4096 * 4);
    bf16_t* Xbf  = (bf16_t*)alloc((size_t)8 * 1024 * 4096 * 2);   // later: Ycht
    bf16_t* Xt   = (bf16_t*)alloc((size_t)16 * 4096 * 512 * 2);
    bf16_t* YtZ  = (bf16_t*)alloc((size_t)8 * 4096 * 1024 * 2);   // Zt early, Yt late
    bf16_t* Cb   = (bf16_t*)alloc((size_t)16 * 64 * 4096 * 2);
    bf16_t* Ctb  = (bf16_t*)alloc((size_t)16 * 4096 * 64 * 2);
    float*  P    = (float*) alloc((size_t)64 * 64 * 512 * 4);
    bf16_t* Dta  = (bf16_t*)alloc((size_t)16 * 64 * 512 * 2);
    bf16_t* Dtb  = (bf16_t*)alloc((size_t)16 * 64 * 512 * 2);
    bf16_t* D2   = (bf16_t*)alloc((size_t)16 * 512 * 64 * 2);
    bf16_t* Zt   = YtZ;
    bf16_t* Yt   = YtZ;
    bf16_t* Ycht = Xbf;

    dim3 blk(256);

    cvt_f32_bf16_k<<<2048, blk, 0, stream>>>(lower_w, Wl, 1024 * 512);
    cvt_f32_bf16_k<<<4096, blk, 0, stream>>>(cheese_w, Wc, 1024 * 1024);
    cvt_f32_bf16_k<<<2048, blk, 0, stream>>>(upper_w, Wu, 512 * 1024);
    prep_k<<<4, blk, 0, stream>>>(ch_gamma, ch_beta, ch_mean, ch_var,
                                  h_gamma, h_beta, h_mean, h_var,
                                  upper_b, coef_ham, chA, chB, hA2, hB2);
    tz_k<<<dim3(64, 8, 8), blk, 0, stream>>>(z, Zt);
    dinit_k<<<dim3(128, 16), blk, 0, stream>>>(Dinit_s, Dinit_c, Dta);

    // G1: X = relu(Wl @ z + b)  -> X [b][1024][4096] and Xt [bs][4096][512]
    g2<128, 128, 2, 2, 1, 0><<<dim3(32, 8, 8), blk, 0, stream>>>(
        Wl, Zt, (void*)Xbf, (void*)Xt, 1024, 4096, 512,
        512, 512, 4096,
        0L, (long)4096 * 512, (long)1024 * 4096, (long)2 * 4096 * 512,
        lower_b, nullptr, nullptr, nullptr, 0L);

    xnorm2_k<<<16384, blk, 0, stream>>>(Xt, xinv);
    dnorm_k<<<256, blk, 0, stream>>>(Dta, dinv);

    bf16_t* cur = Dta;
    bf16_t* nxt = Dtb;
    for (int t = 0; t < 3; ++t) {
        // S + fused softmax -> C [bs][64][4096] (+ Ct on last iter)
        g2<64, 256, 1, 4, 6, 0><<<dim3(16, 1, 16), blk, 0, stream>>>(
            cur, Xt, (void*)Cb, (t == 2) ? (void*)Ctb : nullptr, 64, 4096, 512,
            512, 512, 4096,
            (long)64 * 512, (long)4096 * 512, (long)64 * 4096, (long)4096 * 64,
            dinv, xinv, nullptr, nullptr, 0L);
        // XCt split-K=4 partials: P[bz][r][d] (transposed fp32)
        g2<128, 64, 2, 2, 5, 0><<<dim3(1, 4, 64), blk, 0, stream>>>(
            Xbf, Cb, (void*)P, nullptr, 512, 64, 1024,
            4096, 4096, 512,
            (long)512 * 4096, (long)64 * 4096, (long)64 * 512, 0L,
            nullptr, nullptr, nullptr, nullptr, 0L);
        reduce_k<<<1024, dim3(64), 0, stream>>>(P, nxt, dinv);
        bf16_t* tmp = cur; cur = nxt; nxt = tmp;
    }

    d2_k<<<dim3(128, 16), blk, 0, stream>>>(cur, dinv, D2);

    // Xbar^T = Ct @ D2^T -> Yt [b][4096][1024] (cols s*512+d)
    g2<128, 128, 2, 2, 4, 0><<<dim3(4, 32, 16), blk, 0, stream>>>(
        Ctb, D2, (void*)Yt, nullptr, 4096, 512, 64,
        64, 64, 1024,
        (long)4096 * 64, (long)512 * 64, (long)4096 * 1024, 0L,
        nullptr, nullptr, nullptr, nullptr, 0L);

    // cheese: Ycht[n][c] = relu(bn(Yt[n][:] @ Wc^T))
    g2<128, 128, 2, 2, 2, 0><<<dim3(8, 32, 8), blk, 0, stream>>>(
        Yt, Wc, (void*)Ycht, nullptr, 4096, 1024, 1024,
        1024, 1024, 1024,
        (long)4096 * 1024, 0L, (long)4096 * 1024, 0L,
        chA, chB, nullptr, nullptr, 0L);

    // upper: out = relu(hA2*(Wu @ Ych) + hB2 + cB*z)  fp32  (ORDER=1: B-panel reuse)
    g2<128, 128, 2, 2, 3, 1><<<dim3(32, 4, 8), blk, 0, stream>>>(
        Wu, Ycht, d_out, nullptr, 512, 4096, 1024,
        1024, 1024, 4096,
        0L, (long)4096 * 1024, (long)512 * 4096, 0L,
        hA2, hB2, coef_sc, z, (long)512 * 4096);

    (void)in_sizes; (void)n_in; (void)out_size; (void)ws_size;
}

// Round 4
// 425.022 us; speedup vs baseline: 2.8167x; 1.0696x over previous
//
#include <hip/hip_runtime.h>
#include <hip/hip_bf16.h>

typedef __bf16 bf16_t;
typedef __bf16 bf16x4 __attribute__((ext_vector_type(4)));
typedef __bf16 bf16x8 __attribute__((ext_vector_type(8)));
typedef float  f32x4  __attribute__((ext_vector_type(4)));

#define HEPS 1e-6f

__device__ __forceinline__ void gload16(const bf16_t* g, bf16_t* l) {
    __builtin_amdgcn_global_load_lds(
        (const __attribute__((address_space(1))) unsigned int*)(g),
        (__attribute__((address_space(3))) unsigned int*)(l),
        16, 0, 0);
}

// ---------------- small kernels ----------------

__global__ void cvt_f32_bf16_k(const float* __restrict__ src, bf16_t* __restrict__ dst, int n) {
    int i = blockIdx.x * 256 + threadIdx.x;
    if (i < n) dst[i] = (bf16_t)src[i];
}

__global__ void prep_k(const float* __restrict__ chg, const float* __restrict__ chb,
                       const float* __restrict__ chm, const float* __restrict__ chv,
                       const float* __restrict__ hg, const float* __restrict__ hb,
                       const float* __restrict__ hm, const float* __restrict__ hv,
                       const float* __restrict__ ub, const float* __restrict__ cham,
                       float* __restrict__ chA, float* __restrict__ chB,
                       float* __restrict__ hA2, float* __restrict__ hB2) {
    int i = blockIdx.x * 256 + threadIdx.x;
    if (i < 1024) {
        float inv = chg[i] * rsqrtf(chv[i] + 1e-5f);
        chA[i] = inv;
        chB[i] = chb[i] - chm[i] * inv;
    }
    if (i < 512) {
        float inv = hg[i] * rsqrtf(hv[i] + 1e-5f);
        float cA = cham[0];
        hA2[i] = cA * inv;
        hB2[i] = cA * (fmaf(ub[i], inv, hb[i]) - hm[i] * inv);
    }
}

// z [b][512][4096] fp32 -> Zt [b][4096][512] bf16
__global__ void tz_k(const float* __restrict__ z, bf16_t* __restrict__ Zt) {
    __shared__ bf16_t t[64][68];
    int b = blockIdx.z, kt = blockIdx.y, nt = blockIdx.x;
    const float* src = z + ((size_t)b * 512 + kt * 64) * 4096 + nt * 64;
    int tid = threadIdx.x;
    int kr = tid >> 4;
    int nc = (tid & 15) * 4;
    #pragma unroll
    for (int it = 0; it < 4; ++it) {
        int k = kr + it * 16;
        float4 v = *(const float4*)&src[(size_t)k * 4096 + nc];
        t[nc + 0][k] = (bf16_t)v.x; t[nc + 1][k] = (bf16_t)v.y;
        t[nc + 2][k] = (bf16_t)v.z; t[nc + 3][k] = (bf16_t)v.w;
    }
    __syncthreads();
    bf16_t* dst = Zt + ((size_t)b * 4096 + nt * 64) * 512 + kt * 64;
    int nr = tid >> 4;
    int kc = (tid & 15) * 4;
    #pragma unroll
    for (int it = 0; it < 4; ++it) {
        int n = nr + it * 16;
        bf16x4 o;
        #pragma unroll
        for (int c = 0; c < 4; ++c) o[c] = t[n][kc + c];
        *(bf16x4*)&dst[(size_t)n * 512 + kc] = o;
    }
}

__global__ void dinit_k(const float* __restrict__ Ds, const float* __restrict__ Dc,
                        bf16_t* __restrict__ Dt) {
    int bs = blockIdx.y;
    int b = bs >> 1;
    const float* src = ((bs & 1) ? Dc : Ds) + (size_t)b * 512 * 64;
    int idx = blockIdx.x * 256 + threadIdx.x;
    int r = idx & 63, d = idx >> 6;
    Dt[(size_t)bs * 64 * 512 + (size_t)r * 512 + d] = (bf16_t)src[d * 64 + r];
}

__global__ void xnorm2_k(const bf16_t* __restrict__ Xt, float* __restrict__ xinv) {
    int gid = blockIdx.x * 4 + (threadIdx.x >> 6);
    int lane = threadIdx.x & 63;
    bf16x8 v = *(const bf16x8*)(Xt + (size_t)gid * 512 + lane * 8);
    float s = 0.f;
    #pragma unroll
    for (int e = 0; e < 8; ++e) { float f = (float)v[e]; s += f * f; }
    #pragma unroll
    for (int off = 32; off > 0; off >>= 1) s += __shfl_xor(s, off);
    if (lane == 0) xinv[gid] = 1.0f / (10.0f * fmaxf(sqrtf(s), HEPS));
}

__global__ void dnorm_k(const bf16_t* __restrict__ Dt, float* __restrict__ dinv) {
    int gw = (blockIdx.x * 256 + threadIdx.x) >> 6;
    int lane = threadIdx.x & 63;
    bf16x8 v = *(const bf16x8*)(Dt + (size_t)gw * 512 + lane * 8);
    float s = 0.f;
    #pragma unroll
    for (int e = 0; e < 8; ++e) { float f = (float)v[e]; s += f * f; }
    #pragma unroll
    for (int off = 32; off > 0; off >>= 1) s += __shfl_xor(s, off);
    if (lane == 0) dinv[gw] = 1.0f / fmaxf(sqrtf(s), HEPS);
}

// sum 4 split-K partials -> Dt bf16, plus dinv of summed rows
__global__ void reduce_k(const float* __restrict__ P, bf16_t* __restrict__ Dt,
                         float* __restrict__ dinv) {
    int bsr = blockIdx.x;
    int bs = bsr >> 6, r = bsr & 63;
    int lane = threadIdx.x;
    const float* base = P + ((size_t)(bs * 4) * 64 + r) * 512 + lane * 8;
    float s[8] = {0.f, 0.f, 0.f, 0.f, 0.f, 0.f, 0.f, 0.f};
    #pragma unroll
    for (int kc = 0; kc < 4; ++kc) {
        const float* p = base + (size_t)kc * 64 * 512;
        float4 u = *(const float4*)p;
        float4 w = *(const float4*)(p + 4);
        s[0] += u.x; s[1] += u.y; s[2] += u.z; s[3] += u.w;
        s[4] += w.x; s[5] += w.y; s[6] += w.z; s[7] += w.w;
    }
    bf16x8 o;
    float sq = 0.f;
    #pragma unroll
    for (int e = 0; e < 8; ++e) { sq += s[e] * s[e]; o[e] = (bf16_t)s[e]; }
    *(bf16x8*)&Dt[(size_t)bsr * 512 + lane * 8] = o;
    #pragma unroll
    for (int off = 32; off > 0; off >>= 1) sq += __shfl_xor(sq, off);
    if (lane == 0) dinv[bsr] = 1.0f / fmaxf(sqrtf(sq), HEPS);
}

__global__ void d2_k(const bf16_t* __restrict__ Dt, const float* __restrict__ dinv,
                     bf16_t* __restrict__ D2) {
    int bs = blockIdx.y;
    int idx = blockIdx.x * 256 + threadIdx.x;
    int r = idx >> 9, d = idx & 511;
    float v = (float)Dt[(size_t)bs * 64 * 512 + (size_t)r * 512 + d] * dinv[bs * 64 + r];
    D2[(size_t)bs * 512 * 64 + (size_t)d * 64 + r] = (bf16_t)v;
}

// ---------------- MFMA GEMM (dbuf prefetch pipeline + XCD-chunked swizzle) ----------------
// C[m][n] = sum_k A[m][k]*B^T[n][k]; both operands row-major K-contiguous.
// ORDER 0: x-fast within batch (A-panel reuse)   ORDER 1: y-fast (B-panel reuse)
// EPI 1: G1 (bias+relu, dual store X + Xt)      EPI 2: cheese (col a*x+b, relu, bf16)
// EPI 3: upper (row a*x+b + cB*shortcut, relu, fp32)
// EPI 4: Xbar (bf16 store with (b,s) split)
// EPI 5: XCt split-K partial (transposed fp32)  EPI 6: S + fused column softmax -> C[, Ct]
template<int BM, int BN, int WAVES_M, int WAVES_N, int EPI, int ORDER>
__launch_bounds__(256)
__global__ void g2(const bf16_t* __restrict__ Ag, const bf16_t* __restrict__ Bg,
                   void* __restrict__ Cg, void* __restrict__ C2g,
                   const int M, const int N, const int K,
                   const int ldA, const int ldB, const int ldC,
                   const long aStride, const long bStride,
                   const long cStride, const long c2Stride,
                   const float* __restrict__ p0, const float* __restrict__ p1,
                   const float* __restrict__ scal,
                   const float* __restrict__ shortcut, const long sStride)
{
    constexpr int WM = BM / WAVES_M, WN = BN / WAVES_N;
    constexpr int FM = WM / 16, FN = WN / 16;
    constexpr int ASEG = BM / 64, BSEG = BN / 64;

    __shared__ __align__(64) bf16_t Al[2][BM * 32];
    __shared__ __align__(64) bf16_t Bl[2][BN * 32];
    __shared__ float dl[64];

    const int tid = threadIdx.x;
    const int wave = tid >> 6, lane = tid & 63;
    const int l15 = lane & 15, q = lane >> 4;
    const int lrow = lane >> 2, lcol = (lane & 3) * 8;

    // ---- XCD-chunked bijective remap (m204) ----
    const int gx = gridDim.x, gy = gridDim.y;
    const int per = gx * gy;
    const int nwg = per * gridDim.z;
    const int g = blockIdx.z * per + blockIdx.y * gx + blockIdx.x;
    const int qq = nwg >> 3, rr = nwg & 7;
    const int xcd = g & 7, jj = g >> 3;
    const int w = (xcd < rr ? xcd * (qq + 1) : rr * (qq + 1) + (xcd - rr) * qq) + jj;
    const int bz = w / per;
    const int rem = w - bz * per;
    int bx, by;
    if constexpr (ORDER == 0) { by = rem / gx; bx = rem - by * gx; }
    else                      { bx = rem / gy; by = rem - bx * gy; }

    int bs = bz, ex = 0;
    if constexpr (EPI == 5) { bs = bz >> 2; ex = (bz & 3) * 1024; }

    const int n0 = bx * BN;
    const int m0 = by * BM;
    const int wm0 = (wave / WAVES_N) * WM;
    const int wn0 = (wave % WAVES_N) * WN;

    const bf16_t* Ab = Ag + (size_t)bs * (size_t)aStride + ex;
    const bf16_t* Bb = Bg + (size_t)bs * (size_t)bStride + ex;

    if constexpr (EPI == 6) { if (tid < 64) dl[tid] = p0[bz * 64 + tid]; }

    auto stage = [&](int buf, int k0) {
        #pragma unroll
        for (int t = 0; t < ASEG; ++t) {
            int seg = wave * ASEG + t;
            gload16(Ab + (size_t)(m0 + seg * 16 + lrow) * ldA + k0 + lcol, &Al[buf][seg * 512]);
        }
        #pragma unroll
        for (int t = 0; t < BSEG; ++t) {
            int seg = wave * BSEG + t;
            gload16(Bb + (size_t)(n0 + seg * 16 + lrow) * ldB + k0 + lcol, &Bl[buf][seg * 512]);
        }
    };

    f32x4 acc[FM][FN];
    #pragma unroll
    for (int i = 0; i < FM; ++i)
        #pragma unroll
        for (int j = 0; j < FN; ++j)
            #pragma unroll
            for (int e = 0; e < 4; ++e) acc[i][j][e] = 0.f;

    stage(0, 0);
    __syncthreads();           // drains vmcnt(0): buf0 ready

    const int nK = K / 32;
    int cur = 0;
    for (int kk = 0; kk < nK; ++kk) {
        if (kk + 1 < nK) stage(cur ^ 1, (kk + 1) * 32);   // prefetch overlaps compute

        bf16x8 af[FM], bfm[FN];
        #pragma unroll
        for (int i = 0; i < FM; ++i)
            af[i] = *(const bf16x8*)&Al[cur][(wm0 + 16 * i + l15) * 32 + 8 * q];
        #pragma unroll
        for (int j = 0; j < FN; ++j)
            bfm[j] = *(const bf16x8*)&Bl[cur][(wn0 + 16 * j + l15) * 32 + 8 * q];
        #pragma unroll
        for (int i = 0; i < FM; ++i)
            #pragma unroll
            for (int j = 0; j < FN; ++j)
                acc[i][j] = __builtin_amdgcn_mfma_f32_16x16x32_bf16(af[i], bfm[j], acc[i][j], 0, 0, 0);

        __syncthreads();       // drains vmcnt(0): next buf ready, all reads of cur done
        cur ^= 1;
    }

    int rowB[FM];
    #pragma unroll
    for (int i = 0; i < FM; ++i) rowB[i] = m0 + wm0 + 16 * i + 4 * q;
    const int colBase = n0 + wn0;

    if constexpr (EPI == 1) {
        bf16_t* X  = (bf16_t*)Cg  + (size_t)bz * (size_t)cStride;
        bf16_t* Xt = (bf16_t*)C2g + (size_t)bz * (size_t)c2Stride;
        #pragma unroll
        for (int i = 0; i < FM; ++i) {
            int rb = rowB[i];
            int s = rb >> 9, d0 = rb & 511;
            #pragma unroll
            for (int j = 0; j < FN; ++j) {
                int col = colBase + 16 * j + l15;
                bf16x4 t;
                #pragma unroll
                for (int e = 0; e < 4; ++e) {
                    float v = fmaxf(acc[i][j][e] + p0[rb + e], 0.f);
                    t[e] = (bf16_t)v;
                    X[(size_t)(rb + e) * ldC + col] = t[e];
                }
                *(bf16x4*)&Xt[((size_t)s * 4096 + col) * 512 + d0] = t;
            }
        }
    } else if constexpr (EPI == 2) {
        bf16_t* O = (bf16_t*)Cg + (size_t)bz * (size_t)cStride;
        #pragma unroll
        for (int j = 0; j < FN; ++j) {
            int col = colBase + 16 * j + l15;
            float a = p0[col], b = p1[col];
            #pragma unroll
            for (int i = 0; i < FM; ++i) {
                int rb = rowB[i];
                #pragma unroll
                for (int e = 0; e < 4; ++e) {
                    float v = fmaxf(fmaf(acc[i][j][e], a, b), 0.f);
                    O[(size_t)(rb + e) * ldC + col] = (bf16_t)v;
                }
            }
        }
    } else if constexpr (EPI == 3) {
        float* O = (float*)Cg + (size_t)bz * (size_t)cStride;
        const float* sc = shortcut + (size_t)bz * (size_t)sStride;
        float cB = scal[0];
        #pragma unroll
        for (int i = 0; i < FM; ++i) {
            int rb = rowB[i];
            #pragma unroll
            for (int e = 0; e < 4; ++e) {
                int row = rb + e;
                float a = p0[row], b = p1[row];
                #pragma unroll
                for (int j = 0; j < FN; ++j) {
                    int col = colBase + 16 * j + l15;
                    float v = fmaf(acc[i][j][e], a, b) + cB * sc[(size_t)row * ldC + col];
                    O[(size_t)row * ldC + col] = fmaxf(v, 0.f);
                }
            }
        }
    } else if constexpr (EPI == 4) {
        bf16_t* O = (bf16_t*)Cg + (size_t)(bz >> 1) * (size_t)cStride + (bz & 1) * 512;
        #pragma unroll
        for (int i = 0; i < FM; ++i) {
            int rb = rowB[i];
            #pragma unroll
            for (int j = 0; j < FN; ++j) {
                int col = colBase + 16 * j + l15;
                #pragma unroll
                for (int e = 0; e < 4; ++e)
                    O[(size_t)(rb + e) * ldC + col] = (bf16_t)acc[i][j][e];
            }
        }
    } else if constexpr (EPI == 5) {
        float* O = (float*)Cg + (size_t)bz * (size_t)cStride;
        #pragma unroll
        for (int i = 0; i < FM; ++i) {
            int rb = rowB[i];
            #pragma unroll
            for (int j = 0; j < FN; ++j) {
                int col = colBase + 16 * j + l15;
                *(f32x4*)&O[(size_t)col * ldC + rb] = acc[i][j];
            }
        }
    } else if constexpr (EPI == 6) {
        bf16_t* Cc = (bf16_t*)Cg  + (size_t)bz * (size_t)cStride;
        bf16_t* Ct = (bf16_t*)C2g + (size_t)bz * (size_t)c2Stride;
        const bool doCt = (C2g != nullptr);
        #pragma unroll
        for (int j = 0; j < FN; ++j) {
            int col = colBase + 16 * j + l15;
            float xi = p1[bz * 4096 + col];
            float mx = -1e30f;
            #pragma unroll
            for (int i = 0; i < FM; ++i)
                #pragma unroll
                for (int e = 0; e < 4; ++e) {
                    float v = acc[i][j][e] * dl[rowB[i] + e] * xi;
                    acc[i][j][e] = v;
                    mx = fmaxf(mx, v);
                }
            mx = fmaxf(mx, __shfl_xor(mx, 16));
            mx = fmaxf(mx, __shfl_xor(mx, 32));
            float sm = 0.f;
            #pragma unroll
            for (int i = 0; i < FM; ++i)
                #pragma unroll
                for (int e = 0; e < 4; ++e) {
                    float p = __expf(acc[i][j][e] - mx);
                    acc[i][j][e] = p;
                    sm += p;
                }
            sm += __shfl_xor(sm, 16);
            sm += __shfl_xor(sm, 32);
            float rs = 1.0f / sm;
            #pragma unroll
            for (int i = 0; i < FM; ++i) {
                int rb = rowB[i];
                bf16x4 t;
                #pragma unroll
                for (int e = 0; e < 4; ++e) {
                    t[e] = (bf16_t)(acc[i][j][e] * rs);
                    Cc[(size_t)(rb + e) * ldC + col] = t[e];
                }
                if (doCt) *(bf16x4*)&Ct[(size_t)col * 64 + rb] = t;
            }
        }
    }
}

// ---------------- host launcher ----------------

extern "C" void kernel_launch(void* const* d_in, const int* in_sizes, int n_in,
                              void* d_out, int out_size, void* d_ws, size_t ws_size,
                              hipStream_t stream) {
    const float* z        = (const float*)d_in[0];
    const float* lower_w  = (const float*)d_in[1];
    const float* lower_b  = (const float*)d_in[2];
    const float* Dinit_s  = (const float*)d_in[3];
    const float* Dinit_c  = (const float*)d_in[4];
    const float* cheese_w = (const float*)d_in[5];
    const float* ch_gamma = (const float*)d_in[6];
    const float* ch_beta  = (const float*)d_in[7];
    const float* ch_mean  = (const float*)d_in[8];
    const float* ch_var   = (const float*)d_in[9];
    const float* upper_w  = (const float*)d_in[10];
    const float* upper_b  = (const float*)d_in[11];
    const float* h_gamma  = (const float*)d_in[12];
    const float* h_beta   = (const float*)d_in[13];
    const float* h_mean   = (const float*)d_in[14];
    const float* h_var    = (const float*)d_in[15];
    const float* coef_ham = (const float*)d_in[16];
    const float* coef_sc  = (const float*)d_in[17];

    char* ws = (char*)d_ws;
    size_t off = 0;
    auto alloc = [&](size_t bytes) -> void* {
        void* p = ws + off;
        off += (bytes + 255) & ~(size_t)255;
        return p;
    };

    bf16_t* Wl   = (bf16_t*)alloc((size_t)1024 * 512 * 2);
    bf16_t* Wc   = (bf16_t*)alloc((size_t)1024 * 1024 * 2);
    bf16_t* Wu   = (bf16_t*)alloc((size_t)512 * 1024 * 2);
    float*  chA  = (float*) alloc(1024 * 4);
    float*  chB  = (float*) alloc(1024 * 4);
    float*  hA2  = (float*) alloc(512 * 4);
    float*  hB2  = (float*) alloc(512 * 4);
    float*  dinv = (float*) alloc(1024 * 4);
    float*  xinv = (float*) alloc((size_t)16 * 4096 * 4);
    bf16_t* Xbf  = (bf16_t*)alloc((size_t)8 * 1024 * 4096 * 2);   // later: Ycht
    bf16_t* Xt   = (bf16_t*)alloc((size_t)16 * 4096 * 512 * 2);
    bf16_t* YtZ  = (bf16_t*)alloc((size_t)8 * 4096 * 1024 * 2);   // Zt early, Yt late
    bf16_t* Cb   = (bf16_t*)alloc((size_t)16 * 64 * 4096 * 2);
    bf16_t* Ctb  = (bf16_t*)alloc((size_t)16 * 4096 * 64 * 2);
    float*  P    = (float*) alloc((size_t)64 * 64 * 512 * 4);
    bf16_t* Dta  = (bf16_t*)alloc((size_t)16 * 64 * 512 * 2);
    bf16_t* Dtb  = (bf16_t*)alloc((size_t)16 * 64 * 512 * 2);
    bf16_t* D2   = (bf16_t*)alloc((size_t)16 * 512 * 64 * 2);
    bf16_t* Zt   = YtZ;
    bf16_t* Yt   = YtZ;
    bf16_t* Ycht = Xbf;

    dim3 blk(256);

    cvt_f32_bf16_k<<<2048, blk, 0, stream>>>(lower_w, Wl, 1024 * 512);
    cvt_f32_bf16_k<<<4096, blk, 0, stream>>>(cheese_w, Wc, 1024 * 1024);
    cvt_f32_bf16_k<<<2048, blk, 0, stream>>>(upper_w, Wu, 512 * 1024);
    prep_k<<<4, blk, 0, stream>>>(ch_gamma, ch_beta, ch_mean, ch_var,
                                  h_gamma, h_beta, h_mean, h_var,
                                  upper_b, coef_ham, chA, chB, hA2, hB2);
    tz_k<<<dim3(64, 8, 8), blk, 0, stream>>>(z, Zt);
    dinit_k<<<dim3(128, 16), blk, 0, stream>>>(Dinit_s, Dinit_c, Dta);

    // G1: X = relu(Wl @ z + b)  -> X [b][1024][4096] and Xt [bs][4096][512]
    // ORDER=1: B-panel (Zt) reuse; A=Wl is tiny.
    g2<128, 128, 2, 2, 1, 1><<<dim3(32, 8, 8), blk, 0, stream>>>(
        Wl, Zt, (void*)Xbf, (void*)Xt, 1024, 4096, 512,
        512, 512, 4096,
        0L, (long)4096 * 512, (long)1024 * 4096, (long)2 * 4096 * 512,
        lower_b, nullptr, nullptr, nullptr, 0L);

    xnorm2_k<<<16384, blk, 0, stream>>>(Xt, xinv);
    dnorm_k<<<256, blk, 0, stream>>>(Dta, dinv);

    bf16_t* cur = Dta;
    bf16_t* nxt = Dtb;
    for (int t = 0; t < 3; ++t) {
        // S + fused softmax -> C [bs][64][4096] (+ Ct on last iter)
        g2<64, 256, 1, 4, 6, 0><<<dim3(16, 1, 16), blk, 0, stream>>>(
            cur, Xt, (void*)Cb, (t == 2) ? (void*)Ctb : nullptr, 64, 4096, 512,
            512, 512, 4096,
            (long)64 * 512, (long)4096 * 512, (long)64 * 4096, (long)4096 * 64,
            dinv, xinv, nullptr, nullptr, 0L);
        // XCt split-K=4 partials: P[bz][r][d] (transposed fp32)
        g2<128, 64, 2, 2, 5, 0><<<dim3(1, 4, 64), blk, 0, stream>>>(
            Xbf, Cb, (void*)P, nullptr, 512, 64, 1024,
            4096, 4096, 512,
            (long)512 * 4096, (long)64 * 4096, (long)64 * 512, 0L,
            nullptr, nullptr, nullptr, nullptr, 0L);
        reduce_k<<<1024, dim3(64), 0, stream>>>(P, nxt, dinv);
        bf16_t* tmp = cur; cur = nxt; nxt = tmp;
    }

    d2_k<<<dim3(128, 16), blk, 0, stream>>>(cur, dinv, D2);

    // Xbar^T = Ct @ D2^T -> Yt [b][4096][1024] (cols s*512+d)
    g2<128, 128, 2, 2, 4, 0><<<dim3(4, 32, 16), blk, 0, stream>>>(
        Ctb, D2, (void*)Yt, nullptr, 4096, 512, 64,
        64, 64, 1024,
        (long)4096 * 64, (long)512 * 64, (long)4096 * 1024, 0L,
        nullptr, nullptr, nullptr, nullptr, 0L);

    // cheese: Ycht[n][c] = relu(bn(Yt[n][:] @ Wc^T))
    g2<128, 128, 2, 2, 2, 0><<<dim3(8, 32, 8), blk, 0, stream>>>(
        Yt, Wc, (void*)Ycht, nullptr, 4096, 1024, 1024,
        1024, 1024, 1024,
        (long)4096 * 1024, 0L, (long)4096 * 1024, 0L,
        chA, chB, nullptr, nullptr, 0L);

    // upper: out = relu(hA2*(Wu @ Ych) + hB2 + cB*z)  fp32  (ORDER=1: B-panel reuse)
    g2<128, 128, 2, 2, 3, 1><<<dim3(32, 4, 8), blk, 0, stream>>>(
        Wu, Ycht, d_out, nullptr, 512, 4096, 1024,
        1024, 1024, 4096,
        0L, (long)4096 * 1024, (long)512 * 4096, 0L,
        hA2, hB2, coef_sc, z, (long)512 * 4096);

    (void)in_sizes; (void)n_in; (void)out_size; (void)ws_size;
}